// Round 12
// baseline (295.596 us; speedup 1.0000x reference)
//
#include <hip/hip_runtime.h>
#include <hip/hip_bf16.h>

typedef __attribute__((ext_vector_type(8))) short bf16x8;
typedef __attribute__((ext_vector_type(4))) float f32x4;
typedef __attribute__((ext_vector_type(16))) float f32x16;

#define MFMA16(a, b, c) __builtin_amdgcn_mfma_f32_16x16x32_bf16((a), (b), (c), 0, 0, 0)
#define MFMA32(a, b, c) __builtin_amdgcn_mfma_f32_32x32x16_bf16((a), (b), (c), 0, 0, 0)

#if defined(__has_builtin)
#if __has_builtin(__builtin_amdgcn_exp2f)
#define EXP2(x) __builtin_amdgcn_exp2f(x)
#endif
#endif
#ifndef EXP2
#define EXP2(x) exp2f(x)
#endif

__device__ __forceinline__ short f2b(float f) {
  unsigned u = __builtin_bit_cast(unsigned, f);
  u += 0x7FFFu + ((u >> 16) & 1u);
  return (short)(u >> 16);
}
__device__ __forceinline__ unsigned cvtpk(float lo, float hi) {
  unsigned r;
  asm("v_cvt_pk_bf16_f32 %0, %1, %2" : "=v"(r) : "v"(lo), "v"(hi));
  return r;
}

// ---------------------------------------------------------------- converts
__global__ __launch_bounds__(256) void cvt3_bf16(const float* __restrict__ s0,
                                                 const float* __restrict__ s1,
                                                 const float* __restrict__ s2,
                                                 short* __restrict__ d, long stride) {
  const int which = blockIdx.y;
  const float* s = which == 0 ? s0 : (which == 1 ? s1 : s2);
  long i = (long)blockIdx.x * 256 + threadIdx.x;
  const float4* sp = (const float4*)s;
  float4 a = sp[2 * i], b = sp[2 * i + 1];
  bf16x8 o;
  o[0] = f2b(a.x); o[1] = f2b(a.y); o[2] = f2b(a.z); o[3] = f2b(a.w);
  o[4] = f2b(b.x); o[5] = f2b(b.y); o[6] = f2b(b.z); o[7] = f2b(b.w);
  *(bf16x8*)(d + which * stride + i * 8) = o;
}
__global__ __launch_bounds__(256) void cvt4_bf16(const float* __restrict__ s0,
                                                 const float* __restrict__ s1,
                                                 const float* __restrict__ s2,
                                                 const float* __restrict__ s3,
                                                 short* __restrict__ d, long stride) {
  const int which = blockIdx.y;
  const float* s = which == 0 ? s0 : (which == 1 ? s1 : (which == 2 ? s2 : s3));
  long i = (long)blockIdx.x * 256 + threadIdx.x;
  const float4* sp = (const float4*)s;
  float4 a = sp[2 * i], b = sp[2 * i + 1];
  bf16x8 o;
  o[0] = f2b(a.x); o[1] = f2b(a.y); o[2] = f2b(a.z); o[3] = f2b(a.w);
  o[4] = f2b(b.x); o[5] = f2b(b.y); o[6] = f2b(b.z); o[7] = f2b(b.w);
  *(bf16x8*)(d + which * stride + i * 8) = o;
}

// ---------------------------------------------------------------- GEMM
// Unfused, T1-swizzled, unroll-1 (proven R9-R11). 128x128 tile, 8192x1024x1024.
template <int MODE>
__global__ __launch_bounds__(256) void gemm_bt(const short* __restrict__ A_,
                                               const short* __restrict__ BT_,
                                               void* __restrict__ Cout,
                                               float oscale) {
  __shared__ __align__(16) short As[2][128 * 64];
  __shared__ __align__(16) short Bs[2][128 * 64];
  const int t = threadIdx.x;
  const int l = t & 63, w = t >> 6;
  const int grp = l >> 4, li = l & 15;
  const int wg = (((int)blockIdx.x & 7) << 6) | ((int)blockIdx.x >> 3);  // T1 swizzle
  const int bm = wg >> 3, bn = wg & 7;
  const int m0 = bm << 7, n0 = bn << 7;
  const int wm = (w >> 1) << 6, wn = (w & 1) << 6;
  const int srow = t >> 3, scol = (t & 7) << 3;
  f32x4 acc[4][4] = {};
#pragma unroll
  for (int i = 0; i < 4; ++i) {
    const short* ga = A_ + (long)(m0 + i * 32 + srow) * 1024 + scol;
    __builtin_amdgcn_global_load_lds(
        (const __attribute__((address_space(1))) void*)ga,
        (__attribute__((address_space(3))) void*)&As[0][i * 2048 + t * 8], 16, 0, 0);
    const short* gb = BT_ + (long)(n0 + i * 32 + srow) * 1024 + scol;
    __builtin_amdgcn_global_load_lds(
        (const __attribute__((address_space(1))) void*)gb,
        (__attribute__((address_space(3))) void*)&Bs[0][i * 2048 + t * 8], 16, 0, 0);
  }
  __syncthreads();
#pragma unroll 1
  for (int kt = 0; kt < 16; ++kt) {
    const int cur = kt & 1;
    if (kt + 1 < 16) {
#pragma unroll
      for (int i = 0; i < 4; ++i) {
        const short* ga = A_ + (long)(m0 + i * 32 + srow) * 1024 + (kt + 1) * 64 + scol;
        __builtin_amdgcn_global_load_lds(
            (const __attribute__((address_space(1))) void*)ga,
            (__attribute__((address_space(3))) void*)&As[cur ^ 1][i * 2048 + t * 8], 16, 0, 0);
        const short* gb = BT_ + (long)(n0 + i * 32 + srow) * 1024 + (kt + 1) * 64 + scol;
        __builtin_amdgcn_global_load_lds(
            (const __attribute__((address_space(1))) void*)gb,
            (__attribute__((address_space(3))) void*)&Bs[cur ^ 1][i * 2048 + t * 8], 16, 0, 0);
      }
    }
#pragma unroll
    for (int kk = 0; kk < 64; kk += 32) {
      bf16x8 af[4], bfr[4];
#pragma unroll
      for (int mi = 0; mi < 4; ++mi)
        af[mi] = *(const bf16x8*)&As[cur][(wm + mi * 16 + li) * 64 + kk + grp * 8];
#pragma unroll
      for (int ni = 0; ni < 4; ++ni)
        bfr[ni] = *(const bf16x8*)&Bs[cur][(wn + ni * 16 + li) * 64 + kk + grp * 8];
#pragma unroll
      for (int mi = 0; mi < 4; ++mi)
#pragma unroll
        for (int ni = 0; ni < 4; ++ni)
          acc[mi][ni] = MFMA16(af[mi], bfr[ni], acc[mi][ni]);
    }
    __syncthreads();
  }
#pragma unroll
  for (int mi = 0; mi < 4; ++mi) {
#pragma unroll
    for (int ni = 0; ni < 4; ++ni) {
      f32x4 v = acc[mi][ni];
      int n = n0 + wn + ni * 16 + li;
#pragma unroll
      for (int r = 0; r < 4; ++r) {
        int m = m0 + wm + mi * 16 + grp * 4 + r;
        if (MODE == 2) {
          ((float*)Cout)[(long)m * 1024 + n] = v[r];
        } else {
          int b = m >> 11, sq = m & 2047;
          int h = n >> 6, dh = n & 63;
          if (MODE == 0)
            ((short*)Cout)[(((long)(b * 16 + h) * 2048 + sq) << 6) + dh] = f2b(v[r] * oscale);
          else
            ((short*)Cout)[(((long)(b * 16 + h) * 64 + dh) << 11) + sq] = f2b(v[r]);
        }
      }
    }
  }
}

// ---------------------------------------------------------------- attention v8
// attn_tile math unchanged (proven R6). Re-grid: 2048 blocks x 2 waves;
// 32-row supertile pairs (a, 63-a); each wave carries BOTH members (balanced
// 33 trips/wave); single 16KB K/V buffer; 8 blocks/CU -> 16 waves/CU.
__device__ __forceinline__ void attn_tile(const short* Kbuf, const short* Vbuf,
                                          const bf16x8 qf[4], f32x16& oa, f32x16& ob,
                                          float& mrun, float& lsum, int kt, bool diag,
                                          int khmax, int qg, int q, int hi) {
  f32x16 p0 = {}, p1 = {};
  __builtin_amdgcn_s_setprio(1);
#pragma unroll
  for (int kd = 0; kd < 4; ++kd) {
    int colB = kd * 32 + hi * 16;
    bf16x8 kf0 = *(const bf16x8*)((const char*)Kbuf + q * 128 + (colB ^ ((q & 7) << 4)));
    p0 = MFMA32(kf0, qf[kd], p0);
  }
  if (khmax == 2) {
#pragma unroll
    for (int kd = 0; kd < 4; ++kd) {
      int colB = kd * 32 + hi * 16;
      bf16x8 kf1 = *(const bf16x8*)((const char*)Kbuf + (q + 32) * 128 + (colB ^ ((q & 7) << 4)));
      p1 = MFMA32(kf1, qf[kd], p1);
    }
  }
  __builtin_amdgcn_s_setprio(0);
  if (diag) {
#pragma unroll
    for (int r = 0; r < 16; ++r) {
      int key0 = kt * 64 + (r & 3) + 8 * (r >> 2) + 4 * hi;
      if (key0 > qg) p0[r] = -1e30f;
      if (key0 + 32 > qg) p1[r] = -1e30f;
    }
  }
  float pm = p0[0];
#pragma unroll
  for (int r = 1; r < 16; ++r) pm = fmaxf(pm, p0[r]);
  if (khmax == 2) {
#pragma unroll
    for (int r = 0; r < 16; ++r) pm = fmaxf(pm, p1[r]);
  }
  pm = fmaxf(pm, __shfl_xor(pm, 32));
  const bool skip = __all(pm - mrun <= 11.5f);  // T13 defer-max (log2 units)
  float mn;
  float alpha = 1.f;
  if (skip) {
    mn = mrun;
  } else {
    mn = fmaxf(mrun, pm);
    alpha = EXP2(mrun - mn);
    mrun = mn;
  }
  float ts = 0.f;
#pragma unroll
  for (int r = 0; r < 16; ++r) { p0[r] = EXP2(p0[r] - mn); ts += p0[r]; }
  if (khmax == 2) {
#pragma unroll
    for (int r = 0; r < 16; ++r) { p1[r] = EXP2(p1[r] - mn); ts += p1[r]; }
  }
  ts += __shfl_xor(ts, 32);
  if (skip) {
    lsum += ts;
  } else {
    lsum = lsum * alpha + ts;
#pragma unroll
    for (int r = 0; r < 16; ++r) { oa[r] *= alpha; ob[r] *= alpha; }
  }
  unsigned own0[8], prt0[8], own1[8], prt1[8];
#pragma unroll
  for (int g = 0; g < 4; ++g) {
    own0[2 * g]     = cvtpk(p0[4 * g], p0[4 * g + 1]);
    own0[2 * g + 1] = cvtpk(p0[4 * g + 2], p0[4 * g + 3]);
  }
#pragma unroll
  for (int i = 0; i < 8; ++i) prt0[i] = __shfl_xor(own0[i], 32);
  if (khmax == 2) {
#pragma unroll
    for (int g = 0; g < 4; ++g) {
      own1[2 * g]     = cvtpk(p1[4 * g], p1[4 * g + 1]);
      own1[2 * g + 1] = cvtpk(p1[4 * g + 2], p1[4 * g + 3]);
    }
#pragma unroll
    for (int i = 0; i < 8; ++i) prt1[i] = __shfl_xor(own1[i], 32);
  }
  __builtin_amdgcn_s_setprio(1);
#define PVSTEP(KD, OWN, PRT)                                                              \
  {                                                                                       \
    const int kdl = (KD) & 1;                                                             \
    unsigned b0 = hi ? PRT[4 * kdl + 2] : OWN[4 * kdl];                                   \
    unsigned b1 = hi ? PRT[4 * kdl + 3] : OWN[4 * kdl + 1];                               \
    unsigned b2 = hi ? OWN[4 * kdl + 2] : PRT[4 * kdl];                                   \
    unsigned b3 = hi ? OWN[4 * kdl + 3] : PRT[4 * kdl + 1];                               \
    int4 bi = {(int)b0, (int)b1, (int)b2, (int)b3};                                       \
    bf16x8 pb = __builtin_bit_cast(bf16x8, bi);                                           \
    int colB = (KD) * 32 + hi * 16;                                                       \
    bf16x8 vf0 = *(const bf16x8*)((const char*)Vbuf + q * 128 + (colB ^ ((q & 7) << 4))); \
    bf16x8 vf1 = *(const bf16x8*)((const char*)Vbuf + (q + 32) * 128 + (colB ^ ((q & 7) << 4))); \
    oa = MFMA32(vf0, pb, oa);                                                             \
    ob = MFMA32(vf1, pb, ob);                                                             \
  }
  PVSTEP(0, own0, prt0);
  PVSTEP(1, own0, prt0);
  if (khmax == 2) {
    PVSTEP(2, own1, prt1);
    PVSTEP(3, own1, prt1);
  }
#undef PVSTEP
  __builtin_amdgcn_s_setprio(0);
}

__global__ __launch_bounds__(128, 2) void attn_fwd(const short* __restrict__ Qh,
                                                   const short* __restrict__ Kh,
                                                   const short* __restrict__ Vt,
                                                   short* __restrict__ Xb) {
  __shared__ __align__(16) short Ks[4096];
  __shared__ __align__(16) short Vs[4096];
  const int bh = blockIdx.x;          // 0..63
  const int a  = blockIdx.y;          // 0..31; pair (a, 63-a) of 32-row supertiles
  const int t = threadIdx.x, l = t & 63;
  const int q = l & 31, hi = l >> 5;
  const int sA = a, sB = 63 - a;
  const int qgA = sA * 32 + q, qgB = sB * 32 + q;
  const short* Qp = Qh + (long)bh * 131072;
  const char* Kb = (const char*)(Kh + (long)bh * 131072);
  const char* Vb = (const char*)(Vt + (long)bh * 131072);

  bf16x8 qfA[4], qfB[4];
#pragma unroll
  for (int kd = 0; kd < 4; ++kd) {
    qfA[kd] = *(const bf16x8*)(Qp + (long)qgA * 64 + kd * 16 + hi * 8);
    qfB[kd] = *(const bf16x8*)(Qp + (long)qgB * 64 + kd * 16 + hi * 8);
  }

  f32x16 oaA = {}, obA = {}, oaB = {}, obB = {};
  float mrunA = -1e30f, lsumA = 0.f, mrunB = -1e30f, lsumB = 0.f;
  const int tripsA = (sA >> 1) + 1;
  const int tripsB = (sB >> 1) + 1;
  const int nt = tripsB;  // sB > sA always

  for (int kt = 0; kt < nt; ++kt) {
    // stage 16KB (K 8KB + V 8KB) with 128 threads x 4 chunks x 16B each
#pragma unroll
    for (int c = 0; c < 4; ++c) {
      int o = t * 16 + c * 2048;
      int ksrc = o ^ (((o >> 7) & 7) << 4);
      __builtin_amdgcn_global_load_lds(
          (const __attribute__((address_space(1))) void*)(Kb + (long)kt * 8192 + ksrc),
          (__attribute__((address_space(3))) void*)((char*)Ks + o), 16, 0, 0);
      int row = o >> 7, c16 = (o >> 4) & 7;
      int vsrc = row * 4096 + kt * 128 + ((c16 ^ (row & 7)) << 4);
      __builtin_amdgcn_global_load_lds(
          (const __attribute__((address_space(1))) void*)(Vb + vsrc),
          (__attribute__((address_space(3))) void*)((char*)Vs + o), 16, 0, 0);
    }
    __syncthreads();  // compiler drains vmcnt before barrier -> tile ready

    {
      const bool diag = (kt == tripsB - 1);
      const int khmax = (diag && !(sB & 1)) ? 1 : 2;
      attn_tile(Ks, Vs, qfB, oaB, obB, mrunB, lsumB, kt, diag, khmax, qgB, q, hi);
    }
    if (kt < tripsA) {
      const bool diag = (kt == tripsA - 1);
      const int khmax = (diag && !(sA & 1)) ? 1 : 2;
      attn_tile(Ks, Vs, qfA, oaA, obA, mrunA, lsumA, kt, diag, khmax, qgA, q, hi);
    }
    __syncthreads();  // all reads done before next stage overwrites
  }

  const int b = bh >> 4, h = bh & 15;
#define EPI(OA, OB, LS, QG)                                                \
  {                                                                        \
    const float inv = 1.f / (LS);                                          \
    short* orow = Xb + (long)(b * 2048 + (QG)) * 1024 + h * 64;            \
    _Pragma("unroll") for (int g = 0; g < 4; ++g) {                        \
      unsigned u0 = cvtpk((OA)[4 * g] * inv, (OA)[4 * g + 1] * inv);       \
      unsigned u1 = cvtpk((OA)[4 * g + 2] * inv, (OA)[4 * g + 3] * inv);   \
      uint2 uu = {u0, u1};                                                 \
      *(uint2*)(orow + 8 * g + 4 * hi) = uu;                               \
      unsigned w0 = cvtpk((OB)[4 * g] * inv, (OB)[4 * g + 1] * inv);       \
      unsigned w1 = cvtpk((OB)[4 * g + 2] * inv, (OB)[4 * g + 3] * inv);   \
      uint2 ww = {w0, w1};                                                 \
      *(uint2*)(orow + 32 + 8 * g + 4 * hi) = ww;                          \
    }                                                                      \
  }
  EPI(oaA, obA, lsumA, qgA);
  EPI(oaB, obB, lsumB, qgB);
#undef EPI
}

// ---------------------------------------------------------------- launch
extern "C" void kernel_launch(void* const* d_in, const int* in_sizes, int n_in,
                              void* d_out, int out_size, void* d_ws, size_t ws_size,
                              hipStream_t stream) {
  const float* q  = (const float*)d_in[0];
  const float* k  = (const float*)d_in[1];
  const float* v  = (const float*)d_in[2];
  // d_in[3] = causal tril mask, hardcoded in attn_fwd
  const float* wq = (const float*)d_in[4];
  const float* wk = (const float*)d_in[5];
  const float* wv = (const float*)d_in[6];
  const float* wo = (const float*)d_in[7];

  short* ws = (short*)d_ws;
  const long T = 8388608;  // B*S*D
  short* qb  = ws;
  short* kb  = qb + T;
  short* vb  = kb + T;
  short* Qh  = vb + T;
  short* Kh  = Qh + T;
  short* Vt  = Kh + T;
  short* Xb  = Vt + T;
  short* wqb = Xb + T;
  short* wkb = wqb + 1048576;
  short* wvb = wkb + 1048576;
  short* wob = wvb + 1048576;

  cvt3_bf16<<<dim3(4096, 3), 256, 0, stream>>>(q, k, v, qb, T);
  cvt4_bf16<<<dim3(512, 4), 256, 0, stream>>>(wq, wk, wv, wo, wqb, 1048576);

  // Q pre-scaled by 0.125 * log2(e) for exp2-domain softmax
  gemm_bt<0><<<512, 256, 0, stream>>>(qb, wqb, (void*)Qh, 0.18033688f);
  gemm_bt<0><<<512, 256, 0, stream>>>(kb, wkb, (void*)Kh, 1.0f);
  gemm_bt<1><<<512, 256, 0, stream>>>(vb, wvb, (void*)Vt, 1.0f);
  attn_fwd<<<dim3(64, 32), 128, 0, stream>>>(Qh, Kh, Vt, Xb);
  gemm_bt<2><<<512, 256, 0, stream>>>(Xb, wob, (float*)d_out, 1.0f);
}

// Round 13
// 201.101 us; speedup vs baseline: 1.4699x; 1.4699x over previous
//
#include <hip/hip_runtime.h>
#include <hip/hip_bf16.h>

typedef __attribute__((ext_vector_type(8))) short bf16x8;
typedef __attribute__((ext_vector_type(4))) float f32x4;
typedef __attribute__((ext_vector_type(16))) float f32x16;

#define MFMA16(a, b, c) __builtin_amdgcn_mfma_f32_16x16x32_bf16((a), (b), (c), 0, 0, 0)
#define MFMA32(a, b, c) __builtin_amdgcn_mfma_f32_32x32x16_bf16((a), (b), (c), 0, 0, 0)

#if defined(__has_builtin)
#if __has_builtin(__builtin_amdgcn_exp2f)
#define EXP2(x) __builtin_amdgcn_exp2f(x)
#endif
#endif
#ifndef EXP2
#define EXP2(x) exp2f(x)
#endif

__device__ __forceinline__ short f2b(float f) {
  unsigned u = __builtin_bit_cast(unsigned, f);
  u += 0x7FFFu + ((u >> 16) & 1u);
  return (short)(u >> 16);
}
__device__ __forceinline__ unsigned cvtpk(float lo, float hi) {
  unsigned r;
  asm("v_cvt_pk_bf16_f32 %0, %1, %2" : "=v"(r) : "v"(lo), "v"(hi));
  return r;
}
__device__ __forceinline__ bf16x8 cvt8(float4 a, float4 b) {
  bf16x8 o;
  o[0] = f2b(a.x); o[1] = f2b(a.y); o[2] = f2b(a.z); o[3] = f2b(a.w);
  o[4] = f2b(b.x); o[5] = f2b(b.y); o[6] = f2b(b.z); o[7] = f2b(b.w);
  return o;
}

// ---------------------------------------------------------------- converts (weights only)
__global__ __launch_bounds__(256) void cvt4_bf16(const float* __restrict__ s0,
                                                 const float* __restrict__ s1,
                                                 const float* __restrict__ s2,
                                                 const float* __restrict__ s3,
                                                 short* __restrict__ d, long stride) {
  const int which = blockIdx.y;
  const float* s = which == 0 ? s0 : (which == 1 ? s1 : (which == 2 ? s2 : s3));
  long i = (long)blockIdx.x * 256 + threadIdx.x;
  const float4* sp = (const float4*)s;
  *(bf16x8*)(d + which * stride + i * 8) = cvt8(sp[2 * i], sp[2 * i + 1]);
}

// ---------------------------------------------------------------- projection GEMM
// A is f32 (raw input) — converted to bf16 during LDS staging (kills cvt3 pass).
// B is bf16 weights [N][K], via global_load_lds. T1 swizzle + unroll 1 (proven).
// MODE 0: bf16 head-major [B,H,S,64]; 1: bf16 [B,H,64,S].
template <int MODE>
__global__ __launch_bounds__(256) void gemm_proj(const float* __restrict__ A_,
                                                 const short* __restrict__ BT_,
                                                 short* __restrict__ Cout,
                                                 float oscale) {
  __shared__ __align__(16) short As[2][128 * 64];
  __shared__ __align__(16) short Bs[2][128 * 64];
  const int t = threadIdx.x;
  const int l = t & 63, w = t >> 6;
  const int grp = l >> 4, li = l & 15;
  const int wg = (((int)blockIdx.x & 7) << 6) | ((int)blockIdx.x >> 3);  // T1 swizzle
  const int bm = wg >> 3, bn = wg & 7;
  const int m0 = bm << 7, n0 = bn << 7;
  const int wm = (w >> 1) << 6, wn = (w & 1) << 6;
  const int srow = t >> 3, scol = (t & 7) << 3;
  f32x4 acc[4][4] = {};

  // prologue: stage tile 0
  {
#pragma unroll
    for (int i = 0; i < 4; ++i) {
      const float* ga = A_ + (long)(m0 + i * 32 + srow) * 1024 + scol;
      float4 a0 = *(const float4*)ga, a1 = *(const float4*)(ga + 4);
      *(bf16x8*)&As[0][i * 2048 + t * 8] = cvt8(a0, a1);
      const short* gb = BT_ + (long)(n0 + i * 32 + srow) * 1024 + scol;
      __builtin_amdgcn_global_load_lds(
          (const __attribute__((address_space(1))) void*)gb,
          (__attribute__((address_space(3))) void*)&Bs[0][i * 2048 + t * 8], 16, 0, 0);
    }
  }
  __syncthreads();
#pragma unroll 1
  for (int kt = 0; kt < 16; ++kt) {
    const int cur = kt & 1;
    float4 pf[4][2];
    if (kt + 1 < 16) {
#pragma unroll
      for (int i = 0; i < 4; ++i) {
        const float* ga = A_ + (long)(m0 + i * 32 + srow) * 1024 + (kt + 1) * 64 + scol;
        pf[i][0] = *(const float4*)ga;
        pf[i][1] = *(const float4*)(ga + 4);
        const short* gb = BT_ + (long)(n0 + i * 32 + srow) * 1024 + (kt + 1) * 64 + scol;
        __builtin_amdgcn_global_load_lds(
            (const __attribute__((address_space(1))) void*)gb,
            (__attribute__((address_space(3))) void*)&Bs[cur ^ 1][i * 2048 + t * 8], 16, 0, 0);
      }
    }
#pragma unroll
    for (int kk = 0; kk < 64; kk += 32) {
      bf16x8 af[4], bfr[4];
#pragma unroll
      for (int mi = 0; mi < 4; ++mi)
        af[mi] = *(const bf16x8*)&As[cur][(wm + mi * 16 + li) * 64 + kk + grp * 8];
#pragma unroll
      for (int ni = 0; ni < 4; ++ni)
        bfr[ni] = *(const bf16x8*)&Bs[cur][(wn + ni * 16 + li) * 64 + kk + grp * 8];
#pragma unroll
      for (int mi = 0; mi < 4; ++mi)
#pragma unroll
        for (int ni = 0; ni < 4; ++ni)
          acc[mi][ni] = MFMA16(af[mi], bfr[ni], acc[mi][ni]);
    }
    if (kt + 1 < 16) {
#pragma unroll
      for (int i = 0; i < 4; ++i)
        *(bf16x8*)&As[cur ^ 1][i * 2048 + t * 8] = cvt8(pf[i][0], pf[i][1]);
    }
    __syncthreads();
  }
#pragma unroll
  for (int mi = 0; mi < 4; ++mi) {
#pragma unroll
    for (int ni = 0; ni < 4; ++ni) {
      f32x4 v = acc[mi][ni];
      int n = n0 + wn + ni * 16 + li;
#pragma unroll
      for (int r = 0; r < 4; ++r) {
        int m = m0 + wm + mi * 16 + grp * 4 + r;
        int b = m >> 11, sq = m & 2047;
        int h = n >> 6, dh = n & 63;
        if (MODE == 0)
          Cout[(((long)(b * 16 + h) * 2048 + sq) << 6) + dh] = f2b(v[r] * oscale);
        else
          Cout[(((long)(b * 16 + h) * 64 + dh) << 11) + sq] = f2b(v[r]);
      }
    }
  }
}

// ---------------------------------------------------------------- output GEMM (bf16 A)
__global__ __launch_bounds__(256) void gemm_out(const short* __restrict__ A_,
                                                const short* __restrict__ BT_,
                                                float* __restrict__ Cout) {
  __shared__ __align__(16) short As[2][128 * 64];
  __shared__ __align__(16) short Bs[2][128 * 64];
  const int t = threadIdx.x;
  const int l = t & 63, w = t >> 6;
  const int grp = l >> 4, li = l & 15;
  const int wg = (((int)blockIdx.x & 7) << 6) | ((int)blockIdx.x >> 3);  // T1 swizzle
  const int bm = wg >> 3, bn = wg & 7;
  const int m0 = bm << 7, n0 = bn << 7;
  const int wm = (w >> 1) << 6, wn = (w & 1) << 6;
  const int srow = t >> 3, scol = (t & 7) << 3;
  f32x4 acc[4][4] = {};
#pragma unroll
  for (int i = 0; i < 4; ++i) {
    const short* ga = A_ + (long)(m0 + i * 32 + srow) * 1024 + scol;
    __builtin_amdgcn_global_load_lds(
        (const __attribute__((address_space(1))) void*)ga,
        (__attribute__((address_space(3))) void*)&As[0][i * 2048 + t * 8], 16, 0, 0);
    const short* gb = BT_ + (long)(n0 + i * 32 + srow) * 1024 + scol;
    __builtin_amdgcn_global_load_lds(
        (const __attribute__((address_space(1))) void*)gb,
        (__attribute__((address_space(3))) void*)&Bs[0][i * 2048 + t * 8], 16, 0, 0);
  }
  __syncthreads();
#pragma unroll 1
  for (int kt = 0; kt < 16; ++kt) {
    const int cur = kt & 1;
    if (kt + 1 < 16) {
#pragma unroll
      for (int i = 0; i < 4; ++i) {
        const short* ga = A_ + (long)(m0 + i * 32 + srow) * 1024 + (kt + 1) * 64 + scol;
        __builtin_amdgcn_global_load_lds(
            (const __attribute__((address_space(1))) void*)ga,
            (__attribute__((address_space(3))) void*)&As[cur ^ 1][i * 2048 + t * 8], 16, 0, 0);
        const short* gb = BT_ + (long)(n0 + i * 32 + srow) * 1024 + (kt + 1) * 64 + scol;
        __builtin_amdgcn_global_load_lds(
            (const __attribute__((address_space(1))) void*)gb,
            (__attribute__((address_space(3))) void*)&Bs[cur ^ 1][i * 2048 + t * 8], 16, 0, 0);
      }
    }
#pragma unroll
    for (int kk = 0; kk < 64; kk += 32) {
      bf16x8 af[4], bfr[4];
#pragma unroll
      for (int mi = 0; mi < 4; ++mi)
        af[mi] = *(const bf16x8*)&As[cur][(wm + mi * 16 + li) * 64 + kk + grp * 8];
#pragma unroll
      for (int ni = 0; ni < 4; ++ni)
        bfr[ni] = *(const bf16x8*)&Bs[cur][(wn + ni * 16 + li) * 64 + kk + grp * 8];
#pragma unroll
      for (int mi = 0; mi < 4; ++mi)
#pragma unroll
        for (int ni = 0; ni < 4; ++ni)
          acc[mi][ni] = MFMA16(af[mi], bfr[ni], acc[mi][ni]);
    }
    __syncthreads();
  }
#pragma unroll
  for (int mi = 0; mi < 4; ++mi) {
#pragma unroll
    for (int ni = 0; ni < 4; ++ni) {
      f32x4 v = acc[mi][ni];
      int n = n0 + wn + ni * 16 + li;
#pragma unroll
      for (int r = 0; r < 4; ++r) {
        int m = m0 + wm + mi * 16 + grp * 4 + r;
        Cout[(long)m * 1024 + n] = v[r];
      }
    }
  }
}

// ---------------------------------------------------------------- attention (R11 proven)
__device__ __forceinline__ void attn_tile(const short* Kbuf, const short* Vbuf,
                                          const bf16x8 qf[4], f32x16& oa, f32x16& ob,
                                          float& mrun, float& lsum, int kt, bool diag,
                                          int khmax, int qg, int q, int hi) {
  f32x16 p0 = {}, p1 = {};
  __builtin_amdgcn_s_setprio(1);
#pragma unroll
  for (int kd = 0; kd < 4; ++kd) {
    int colB = kd * 32 + hi * 16;
    bf16x8 kf0 = *(const bf16x8*)((const char*)Kbuf + q * 128 + (colB ^ ((q & 7) << 4)));
    p0 = MFMA32(kf0, qf[kd], p0);
  }
  if (khmax == 2) {
#pragma unroll
    for (int kd = 0; kd < 4; ++kd) {
      int colB = kd * 32 + hi * 16;
      bf16x8 kf1 = *(const bf16x8*)((const char*)Kbuf + (q + 32) * 128 + (colB ^ ((q & 7) << 4)));
      p1 = MFMA32(kf1, qf[kd], p1);
    }
  }
  __builtin_amdgcn_s_setprio(0);
  if (diag) {
#pragma unroll
    for (int r = 0; r < 16; ++r) {
      int key0 = kt * 64 + (r & 3) + 8 * (r >> 2) + 4 * hi;
      if (key0 > qg) p0[r] = -1e30f;
      if (key0 + 32 > qg) p1[r] = -1e30f;
    }
  }
  float pm = p0[0];
#pragma unroll
  for (int r = 1; r < 16; ++r) pm = fmaxf(pm, p0[r]);
  if (khmax == 2) {
#pragma unroll
    for (int r = 0; r < 16; ++r) pm = fmaxf(pm, p1[r]);
  }
  pm = fmaxf(pm, __shfl_xor(pm, 32));
  const bool skip = __all(pm - mrun <= 11.5f);  // T13 defer-max (log2 units)
  float mn;
  float alpha = 1.f;
  if (skip) {
    mn = mrun;
  } else {
    mn = fmaxf(mrun, pm);
    alpha = EXP2(mrun - mn);
    mrun = mn;
  }
  float ts = 0.f;
#pragma unroll
  for (int r = 0; r < 16; ++r) { p0[r] = EXP2(p0[r] - mn); ts += p0[r]; }
  if (khmax == 2) {
#pragma unroll
    for (int r = 0; r < 16; ++r) { p1[r] = EXP2(p1[r] - mn); ts += p1[r]; }
  }
  ts += __shfl_xor(ts, 32);
  if (skip) {
    lsum += ts;
  } else {
    lsum = lsum * alpha + ts;
#pragma unroll
    for (int r = 0; r < 16; ++r) { oa[r] *= alpha; ob[r] *= alpha; }
  }
  unsigned own0[8], prt0[8], own1[8], prt1[8];
#pragma unroll
  for (int g = 0; g < 4; ++g) {
    own0[2 * g]     = cvtpk(p0[4 * g], p0[4 * g + 1]);
    own0[2 * g + 1] = cvtpk(p0[4 * g + 2], p0[4 * g + 3]);
  }
#pragma unroll
  for (int i = 0; i < 8; ++i) prt0[i] = __shfl_xor(own0[i], 32);
  if (khmax == 2) {
#pragma unroll
    for (int g = 0; g < 4; ++g) {
      own1[2 * g]     = cvtpk(p1[4 * g], p1[4 * g + 1]);
      own1[2 * g + 1] = cvtpk(p1[4 * g + 2], p1[4 * g + 3]);
    }
#pragma unroll
    for (int i = 0; i < 8; ++i) prt1[i] = __shfl_xor(own1[i], 32);
  }
  __builtin_amdgcn_s_setprio(1);
#define PVSTEP(KD, OWN, PRT)                                                              \
  {                                                                                       \
    const int kdl = (KD) & 1;                                                             \
    unsigned b0 = hi ? PRT[4 * kdl + 2] : OWN[4 * kdl];                                   \
    unsigned b1 = hi ? PRT[4 * kdl + 3] : OWN[4 * kdl + 1];                               \
    unsigned b2 = hi ? OWN[4 * kdl + 2] : PRT[4 * kdl];                                   \
    unsigned b3 = hi ? OWN[4 * kdl + 3] : PRT[4 * kdl + 1];                               \
    int4 bi = {(int)b0, (int)b1, (int)b2, (int)b3};                                       \
    bf16x8 pb = __builtin_bit_cast(bf16x8, bi);                                           \
    int colB = (KD) * 32 + hi * 16;                                                       \
    bf16x8 vf0 = *(const bf16x8*)((const char*)Vbuf + q * 128 + (colB ^ ((q & 7) << 4))); \
    bf16x8 vf1 = *(const bf16x8*)((const char*)Vbuf + (q + 32) * 128 + (colB ^ ((q & 7) << 4))); \
    oa = MFMA32(vf0, pb, oa);                                                             \
    ob = MFMA32(vf1, pb, ob);                                                             \
  }
  PVSTEP(0, own0, prt0);
  PVSTEP(1, own0, prt0);
  if (khmax == 2) {
    PVSTEP(2, own1, prt1);
    PVSTEP(3, own1, prt1);
  }
#undef PVSTEP
  __builtin_amdgcn_s_setprio(0);
}

__global__ __launch_bounds__(256, 2) void attn_fwd(const short* __restrict__ Qh,
                                                   const short* __restrict__ Kh,
                                                   const short* __restrict__ Vt,
                                                   short* __restrict__ Xb) {
  __shared__ __align__(16) short Ks[2][4096];
  __shared__ __align__(16) short Vs[2][4096];
  const int bh = blockIdx.x;
  const int qtA = blockIdx.y;        // 0..7 (light)
  const int qtB = 15 - qtA;          // heavy partner
  const int t = threadIdx.x, l = t & 63, w = t >> 6;
  const int q = l & 31, hi = l >> 5;
  const int q0wA = qtA * 128 + w * 32, q0wB = qtB * 128 + w * 32;
  const int qgA = q0wA + q, qgB = q0wB + q;
  const short* Qp = Qh + (long)bh * 131072;
  const char* Kb = (const char*)(Kh + (long)bh * 131072);
  const char* Vb = (const char*)(Vt + (long)bh * 131072);

  bf16x8 qfA[4], qfB[4];
#pragma unroll
  for (int kd = 0; kd < 4; ++kd) {
    qfA[kd] = *(const bf16x8*)(Qp + (long)qgA * 64 + kd * 16 + hi * 8);
    qfB[kd] = *(const bf16x8*)(Qp + (long)qgB * 64 + kd * 16 + hi * 8);
  }

  const int co0 = t * 16, co1 = co0 + 4096;

  f32x16 oaA = {}, obA = {}, oaB = {}, obB = {};
  float mrunA = -1e30f, lsumA = 0.f, mrunB = -1e30f, lsumB = 0.f;
  const int tripsA = (q0wA >> 6) + 1;
  const int tripsB = (q0wB >> 6) + 1;
  const int nt = 2 * qtB + 2;

#define STAGE(KT, BUF)                                                                   \
  {                                                                                      \
    long ktb = (long)(KT) * 8192;                                                        \
    _Pragma("unroll") for (int c = 0; c < 2; ++c) {                                      \
      int o = c ? co1 : co0;                                                             \
      int ksrc = o ^ (((o >> 7) & 7) << 4);                                              \
      __builtin_amdgcn_global_load_lds(                                                  \
          (const __attribute__((address_space(1))) void*)(Kb + ktb + ksrc),              \
          (__attribute__((address_space(3))) void*)((char*)Ks[BUF] + o), 16, 0, 0);      \
      int row = o >> 7, c16 = (o >> 4) & 7;                                              \
      int vsrc = row * 4096 + (KT) * 128 + (((c16 ^ (row & 7))) << 4);                   \
      __builtin_amdgcn_global_load_lds(                                                  \
          (const __attribute__((address_space(1))) void*)(Vb + vsrc),                    \
          (__attribute__((address_space(3))) void*)((char*)Vs[BUF] + o), 16, 0, 0);      \
    }                                                                                    \
  }

  STAGE(0, 0);
  __syncthreads();

  for (int kt = 0; kt < nt; ++kt) {
    const int buf = kt & 1;
    if (kt + 1 < nt) STAGE(kt + 1, buf ^ 1);

    if (kt < tripsB) {
      const bool diag = (kt == tripsB - 1);
      const int khmax = (diag && ((q0wB & 32) == 0)) ? 1 : 2;
      attn_tile(Ks[buf], Vs[buf], qfB, oaB, obB, mrunB, lsumB, kt, diag, khmax, qgB, q, hi);
    }
    if (kt < tripsA) {
      const bool diag = (kt == tripsA - 1);
      const int khmax = (diag && ((q0wA & 32) == 0)) ? 1 : 2;
      attn_tile(Ks[buf], Vs[buf], qfA, oaA, obA, mrunA, lsumA, kt, diag, khmax, qgA, q, hi);
    }
    __syncthreads();
  }

  const int b = bh >> 4, h = bh & 15;
#define EPI(OA, OB, LS, QG)                                                \
  {                                                                        \
    const float inv = 1.f / (LS);                                          \
    short* orow = Xb + (long)(b * 2048 + (QG)) * 1024 + h * 64;            \
    _Pragma("unroll") for (int g = 0; g < 4; ++g) {                        \
      unsigned u0 = cvtpk((OA)[4 * g] * inv, (OA)[4 * g + 1] * inv);       \
      unsigned u1 = cvtpk((OA)[4 * g + 2] * inv, (OA)[4 * g + 3] * inv);   \
      uint2 uu = {u0, u1};                                                 \
      *(uint2*)(orow + 8 * g + 4 * hi) = uu;                               \
      unsigned w0 = cvtpk((OB)[4 * g] * inv, (OB)[4 * g + 1] * inv);       \
      unsigned w1 = cvtpk((OB)[4 * g + 2] * inv, (OB)[4 * g + 3] * inv);   \
      uint2 ww = {w0, w1};                                                 \
      *(uint2*)(orow + 32 + 8 * g + 4 * hi) = ww;                          \
    }                                                                      \
  }
  EPI(oaA, obA, lsumA, qgA);
  EPI(oaB, obB, lsumB, qgB);
#undef EPI
}

// ---------------------------------------------------------------- launch
extern "C" void kernel_launch(void* const* d_in, const int* in_sizes, int n_in,
                              void* d_out, int out_size, void* d_ws, size_t ws_size,
                              hipStream_t stream) {
  const float* q  = (const float*)d_in[0];
  const float* k  = (const float*)d_in[1];
  const float* v  = (const float*)d_in[2];
  // d_in[3] = causal tril mask, hardcoded in attn_fwd
  const float* wq = (const float*)d_in[4];
  const float* wk = (const float*)d_in[5];
  const float* wv = (const float*)d_in[6];
  const float* wo = (const float*)d_in[7];

  short* ws = (short*)d_ws;
  const long T = 8388608;  // B*S*D
  short* Qh  = ws;
  short* Kh  = Qh + T;
  short* Vt  = Kh + T;
  short* Xb  = Vt + T;
  short* wqb = Xb + T;
  short* wkb = wqb + 1048576;
  short* wvb = wkb + 1048576;
  short* wob = wvb + 1048576;

  cvt4_bf16<<<dim3(512, 4), 256, 0, stream>>>(wq, wk, wv, wo, wqb, 1048576);

  // Q pre-scaled by 0.125 * log2(e) for exp2-domain softmax.
  // f32 inputs converted in-GEMM during A-staging (cvt3 pass eliminated).
  gemm_proj<0><<<512, 256, 0, stream>>>(q, wqb, Qh, 0.18033688f);
  gemm_proj<0><<<512, 256, 0, stream>>>(k, wkb, Kh, 1.0f);
  gemm_proj<1><<<512, 256, 0, stream>>>(v, wvb, Vt, 1.0f);
  attn_fwd<<<dim3(64, 8), 256, 0, stream>>>(Qh, Kh, Vt, Xb);
  gemm_out<<<512, 256, 0, stream>>>(Xb, wob, (float*)d_out);
}

// Round 14
// 198.980 us; speedup vs baseline: 1.4856x; 1.0107x over previous
//
#include <hip/hip_runtime.h>
#include <hip/hip_bf16.h>

typedef __attribute__((ext_vector_type(8))) short bf16x8;
typedef __attribute__((ext_vector_type(4))) float f32x4;
typedef __attribute__((ext_vector_type(16))) float f32x16;

#define MFMA16(a, b, c) __builtin_amdgcn_mfma_f32_16x16x32_bf16((a), (b), (c), 0, 0, 0)
#define MFMA32(a, b, c) __builtin_amdgcn_mfma_f32_32x32x16_bf16((a), (b), (c), 0, 0, 0)

#if defined(__has_builtin)
#if __has_builtin(__builtin_amdgcn_exp2f)
#define EXP2(x) __builtin_amdgcn_exp2f(x)
#endif
#endif
#ifndef EXP2
#define EXP2(x) exp2f(x)
#endif

__device__ __forceinline__ short f2b(float f) {
  unsigned u = __builtin_bit_cast(unsigned, f);
  u += 0x7FFFu + ((u >> 16) & 1u);
  return (short)(u >> 16);
}
__device__ __forceinline__ unsigned cvtpk(float lo, float hi) {
  unsigned r;
  asm("v_cvt_pk_bf16_f32 %0, %1, %2" : "=v"(r) : "v"(lo), "v"(hi));
  return r;
}
__device__ __forceinline__ bf16x8 cvt8(float4 a, float4 b) {
  bf16x8 o;
  o[0] = f2b(a.x); o[1] = f2b(a.y); o[2] = f2b(a.z); o[3] = f2b(a.w);
  o[4] = f2b(b.x); o[5] = f2b(b.y); o[6] = f2b(b.z); o[7] = f2b(b.w);
  return o;
}

// ---------------------------------------------------------------- converts (weights only)
__global__ __launch_bounds__(256) void cvt4_bf16(const float* __restrict__ s0,
                                                 const float* __restrict__ s1,
                                                 const float* __restrict__ s2,
                                                 const float* __restrict__ s3,
                                                 short* __restrict__ d, long stride) {
  const int which = blockIdx.y;
  const float* s = which == 0 ? s0 : (which == 1 ? s1 : (which == 2 ? s2 : s3));
  long i = (long)blockIdx.x * 256 + threadIdx.x;
  const float4* sp = (const float4*)s;
  *(bf16x8*)(d + which * stride + i * 8) = cvt8(sp[2 * i], sp[2 * i + 1]);
}

// ---------------------------------------------------------------- projection GEMM
// Single-buffer LDS (32KB -> 3 blocks/CU) + T14 async split: A(f32)+B(bf16)
// global->reg loads for kt+1 issued BEFORE compute(kt); cvt+ds_write after
// the read-barrier. A converted f32->bf16 in-flight (no cvt3 pass).
// MODE 0: bf16 head-major [B,H,S,64]; 1: bf16 [B,H,64,S].
template <int MODE>
__global__ __launch_bounds__(256) void gemm_proj(const float* __restrict__ A_,
                                                 const short* __restrict__ BT_,
                                                 short* __restrict__ Cout,
                                                 float oscale) {
  __shared__ __align__(16) short As[128 * 64];
  __shared__ __align__(16) short Bs[128 * 64];
  const int t = threadIdx.x;
  const int l = t & 63, w = t >> 6;
  const int grp = l >> 4, li = l & 15;
  const int wg = (((int)blockIdx.x & 7) << 6) | ((int)blockIdx.x >> 3);  // T1 swizzle
  const int bm = wg >> 3, bn = wg & 7;
  const int m0 = bm << 7, n0 = bn << 7;
  const int wm = (w >> 1) << 6, wn = (w & 1) << 6;
  const int srow = t >> 3, scol = (t & 7) << 3;
  f32x4 acc[4][4] = {};

  float4 pa[4][2];
  bf16x8 pb[4];
#define PLOAD(KT)                                                            \
  {                                                                          \
    _Pragma("unroll") for (int i = 0; i < 4; ++i) {                          \
      const float* ga = A_ + (long)(m0 + i * 32 + srow) * 1024 + (KT) * 64 + scol; \
      pa[i][0] = *(const float4*)ga;                                         \
      pa[i][1] = *(const float4*)(ga + 4);                                   \
      pb[i] = *(const bf16x8*)(BT_ + (long)(n0 + i * 32 + srow) * 1024 + (KT) * 64 + scol); \
    }                                                                        \
  }
#define PWRITE()                                                             \
  {                                                                          \
    _Pragma("unroll") for (int i = 0; i < 4; ++i) {                          \
      *(bf16x8*)&As[i * 2048 + t * 8] = cvt8(pa[i][0], pa[i][1]);            \
      *(bf16x8*)&Bs[i * 2048 + t * 8] = pb[i];                               \
    }                                                                        \
  }

  PLOAD(0);
  PWRITE();
  __syncthreads();
#pragma unroll 1
  for (int kt = 0; kt < 16; ++kt) {
    if (kt + 1 < 16) PLOAD(kt + 1);  // in flight during compute (T14)
#pragma unroll
    for (int kk = 0; kk < 64; kk += 32) {
      bf16x8 af[4], bfr[4];
#pragma unroll
      for (int mi = 0; mi < 4; ++mi)
        af[mi] = *(const bf16x8*)&As[(wm + mi * 16 + li) * 64 + kk + grp * 8];
#pragma unroll
      for (int ni = 0; ni < 4; ++ni)
        bfr[ni] = *(const bf16x8*)&Bs[(wn + ni * 16 + li) * 64 + kk + grp * 8];
#pragma unroll
      for (int mi = 0; mi < 4; ++mi)
#pragma unroll
        for (int ni = 0; ni < 4; ++ni)
          acc[mi][ni] = MFMA16(af[mi], bfr[ni], acc[mi][ni]);
    }
    __syncthreads();  // all waves done reading As/Bs
    if (kt + 1 < 16) {
      PWRITE();
      __syncthreads();  // ds_writes visible
    }
  }
#undef PLOAD
#undef PWRITE
#pragma unroll
  for (int mi = 0; mi < 4; ++mi) {
#pragma unroll
    for (int ni = 0; ni < 4; ++ni) {
      f32x4 v = acc[mi][ni];
      int n = n0 + wn + ni * 16 + li;
#pragma unroll
      for (int r = 0; r < 4; ++r) {
        int m = m0 + wm + mi * 16 + grp * 4 + r;
        int b = m >> 11, sq = m & 2047;
        int h = n >> 6, dh = n & 63;
        if (MODE == 0)
          Cout[(((long)(b * 16 + h) * 2048 + sq) << 6) + dh] = f2b(v[r] * oscale);
        else
          Cout[(((long)(b * 16 + h) * 64 + dh) << 11) + sq] = f2b(v[r]);
      }
    }
  }
}

// ---------------------------------------------------------------- output GEMM
// m97-faithful single-buffer: STAGE -> sync -> compute -> sync. 32KB LDS ->
// 4 blocks/CU target (implicit cross-block overlap covers barrier drain, m114).
__global__ __launch_bounds__(256) void gemm_out(const short* __restrict__ A_,
                                                const short* __restrict__ BT_,
                                                float* __restrict__ Cout) {
  __shared__ __align__(16) short As[128 * 64];
  __shared__ __align__(16) short Bs[128 * 64];
  const int t = threadIdx.x;
  const int l = t & 63, w = t >> 6;
  const int grp = l >> 4, li = l & 15;
  const int wg = (((int)blockIdx.x & 7) << 6) | ((int)blockIdx.x >> 3);  // T1 swizzle
  const int bm = wg >> 3, bn = wg & 7;
  const int m0 = bm << 7, n0 = bn << 7;
  const int wm = (w >> 1) << 6, wn = (w & 1) << 6;
  const int srow = t >> 3, scol = (t & 7) << 3;
  f32x4 acc[4][4] = {};
#pragma unroll 1
  for (int kt = 0; kt < 16; ++kt) {
#pragma unroll
    for (int i = 0; i < 4; ++i) {
      const short* ga = A_ + (long)(m0 + i * 32 + srow) * 1024 + kt * 64 + scol;
      __builtin_amdgcn_global_load_lds(
          (const __attribute__((address_space(1))) void*)ga,
          (__attribute__((address_space(3))) void*)&As[i * 2048 + t * 8], 16, 0, 0);
      const short* gb = BT_ + (long)(n0 + i * 32 + srow) * 1024 + kt * 64 + scol;
      __builtin_amdgcn_global_load_lds(
          (const __attribute__((address_space(1))) void*)gb,
          (__attribute__((address_space(3))) void*)&Bs[i * 2048 + t * 8], 16, 0, 0);
    }
    __syncthreads();
#pragma unroll
    for (int kk = 0; kk < 64; kk += 32) {
      bf16x8 af[4], bfr[4];
#pragma unroll
      for (int mi = 0; mi < 4; ++mi)
        af[mi] = *(const bf16x8*)&As[(wm + mi * 16 + li) * 64 + kk + grp * 8];
#pragma unroll
      for (int ni = 0; ni < 4; ++ni)
        bfr[ni] = *(const bf16x8*)&Bs[(wn + ni * 16 + li) * 64 + kk + grp * 8];
#pragma unroll
      for (int mi = 0; mi < 4; ++mi)
#pragma unroll
        for (int ni = 0; ni < 4; ++ni)
          acc[mi][ni] = MFMA16(af[mi], bfr[ni], acc[mi][ni]);
    }
    __syncthreads();
  }
#pragma unroll
  for (int mi = 0; mi < 4; ++mi) {
#pragma unroll
    for (int ni = 0; ni < 4; ++ni) {
      f32x4 v = acc[mi][ni];
      int n = n0 + wn + ni * 16 + li;
#pragma unroll
      for (int r = 0; r < 4; ++r) {
        int m = m0 + wm + mi * 16 + grp * 4 + r;
        Cout[(long)m * 1024 + n] = v[r];
      }
    }
  }
}

// ---------------------------------------------------------------- attention (R11 proven)
__device__ __forceinline__ void attn_tile(const short* Kbuf, const short* Vbuf,
                                          const bf16x8 qf[4], f32x16& oa, f32x16& ob,
                                          float& mrun, float& lsum, int kt, bool diag,
                                          int khmax, int qg, int q, int hi) {
  f32x16 p0 = {}, p1 = {};
  __builtin_amdgcn_s_setprio(1);
#pragma unroll
  for (int kd = 0; kd < 4; ++kd) {
    int colB = kd * 32 + hi * 16;
    bf16x8 kf0 = *(const bf16x8*)((const char*)Kbuf + q * 128 + (colB ^ ((q & 7) << 4)));
    p0 = MFMA32(kf0, qf[kd], p0);
  }
  if (khmax == 2) {
#pragma unroll
    for (int kd = 0; kd < 4; ++kd) {
      int colB = kd * 32 + hi * 16;
      bf16x8 kf1 = *(const bf16x8*)((const char*)Kbuf + (q + 32) * 128 + (colB ^ ((q & 7) << 4)));
      p1 = MFMA32(kf1, qf[kd], p1);
    }
  }
  __builtin_amdgcn_s_setprio(0);
  if (diag) {
#pragma unroll
    for (int r = 0; r < 16; ++r) {
      int key0 = kt * 64 + (r & 3) + 8 * (r >> 2) + 4 * hi;
      if (key0 > qg) p0[r] = -1e30f;
      if (key0 + 32 > qg) p1[r] = -1e30f;
    }
  }
  float pm = p0[0];
#pragma unroll
  for (int r = 1; r < 16; ++r) pm = fmaxf(pm, p0[r]);
  if (khmax == 2) {
#pragma unroll
    for (int r = 0; r < 16; ++r) pm = fmaxf(pm, p1[r]);
  }
  pm = fmaxf(pm, __shfl_xor(pm, 32));
  const bool skip = __all(pm - mrun <= 11.5f);  // T13 defer-max (log2 units)
  float mn;
  float alpha = 1.f;
  if (skip) {
    mn = mrun;
  } else {
    mn = fmaxf(mrun, pm);
    alpha = EXP2(mrun - mn);
    mrun = mn;
  }
  float ts = 0.f;
#pragma unroll
  for (int r = 0; r < 16; ++r) { p0[r] = EXP2(p0[r] - mn); ts += p0[r]; }
  if (khmax == 2) {
#pragma unroll
    for (int r = 0; r < 16; ++r) { p1[r] = EXP2(p1[r] - mn); ts += p1[r]; }
  }
  ts += __shfl_xor(ts, 32);
  if (skip) {
    lsum += ts;
  } else {
    lsum = lsum * alpha + ts;
#pragma unroll
    for (int r = 0; r < 16; ++r) { oa[r] *= alpha; ob[r] *= alpha; }
  }
  unsigned own0[8], prt0[8], own1[8], prt1[8];
#pragma unroll
  for (int g = 0; g < 4; ++g) {
    own0[2 * g]     = cvtpk(p0[4 * g], p0[4 * g + 1]);
    own0[2 * g + 1] = cvtpk(p0[4 * g + 2], p0[4 * g + 3]);
  }
#pragma unroll
  for (int i = 0; i < 8; ++i) prt0[i] = __shfl_xor(own0[i], 32);
  if (khmax == 2) {
#pragma unroll
    for (int g = 0; g < 4; ++g) {
      own1[2 * g]     = cvtpk(p1[4 * g], p1[4 * g + 1]);
      own1[2 * g + 1] = cvtpk(p1[4 * g + 2], p1[4 * g + 3]);
    }
#pragma unroll
    for (int i = 0; i < 8; ++i) prt1[i] = __shfl_xor(own1[i], 32);
  }
  __builtin_amdgcn_s_setprio(1);
#define PVSTEP(KD, OWN, PRT)                                                              \
  {                                                                                       \
    const int kdl = (KD) & 1;                                                             \
    unsigned b0 = hi ? PRT[4 * kdl + 2] : OWN[4 * kdl];                                   \
    unsigned b1 = hi ? PRT[4 * kdl + 3] : OWN[4 * kdl + 1];                               \
    unsigned b2 = hi ? OWN[4 * kdl + 2] : PRT[4 * kdl];                                   \
    unsigned b3 = hi ? OWN[4 * kdl + 3] : PRT[4 * kdl + 1];                               \
    int4 bi = {(int)b0, (int)b1, (int)b2, (int)b3};                                       \
    bf16x8 pb = __builtin_bit_cast(bf16x8, bi);                                           \
    int colB = (KD) * 32 + hi * 16;                                                       \
    bf16x8 vf0 = *(const bf16x8*)((const char*)Vbuf + q * 128 + (colB ^ ((q & 7) << 4))); \
    bf16x8 vf1 = *(const bf16x8*)((const char*)Vbuf + (q + 32) * 128 + (colB ^ ((q & 7) << 4))); \
    oa = MFMA32(vf0, pb, oa);                                                             \
    ob = MFMA32(vf1, pb, ob);                                                             \
  }
  PVSTEP(0, own0, prt0);
  PVSTEP(1, own0, prt0);
  if (khmax == 2) {
    PVSTEP(2, own1, prt1);
    PVSTEP(3, own1, prt1);
  }
#undef PVSTEP
  __builtin_amdgcn_s_setprio(0);
}

__global__ __launch_bounds__(256, 2) void attn_fwd(const short* __restrict__ Qh,
                                                   const short* __restrict__ Kh,
                                                   const short* __restrict__ Vt,
                                                   short* __restrict__ Xb) {
  __shared__ __align__(16) short Ks[2][4096];
  __shared__ __align__(16) short Vs[2][4096];
  const int bh = blockIdx.x;
  const int qtA = blockIdx.y;        // 0..7 (light)
  const int qtB = 15 - qtA;          // heavy partner
  const int t = threadIdx.x, l = t & 63, w = t >> 6;
  const int q = l & 31, hi = l >> 5;
  const int q0wA = qtA * 128 + w * 32, q0wB = qtB * 128 + w * 32;
  const int qgA = q0wA + q, qgB = q0wB + q;
  const short* Qp = Qh + (long)bh * 131072;
  const char* Kb = (const char*)(Kh + (long)bh * 131072);
  const char* Vb = (const char*)(Vt + (long)bh * 131072);

  bf16x8 qfA[4], qfB[4];
#pragma unroll
  for (int kd = 0; kd < 4; ++kd) {
    qfA[kd] = *(const bf16x8*)(Qp + (long)qgA * 64 + kd * 16 + hi * 8);
    qfB[kd] = *(const bf16x8*)(Qp + (long)qgB * 64 + kd * 16 + hi * 8);
  }

  const int co0 = t * 16, co1 = co0 + 4096;

  f32x16 oaA = {}, obA = {}, oaB = {}, obB = {};
  float mrunA = -1e30f, lsumA = 0.f, mrunB = -1e30f, lsumB = 0.f;
  const int tripsA = (q0wA >> 6) + 1;
  const int tripsB = (q0wB >> 6) + 1;
  const int nt = 2 * qtB + 2;

#define STAGE(KT, BUF)                                                                   \
  {                                                                                      \
    long ktb = (long)(KT) * 8192;                                                        \
    _Pragma("unroll") for (int c = 0; c < 2; ++c) {                                      \
      int o = c ? co1 : co0;                                                             \
      int ksrc = o ^ (((o >> 7) & 7) << 4);                                              \
      __builtin_amdgcn_global_load_lds(                                                  \
          (const __attribute__((address_space(1))) void*)(Kb + ktb + ksrc),              \
          (__attribute__((address_space(3))) void*)((char*)Ks[BUF] + o), 16, 0, 0);      \
      int row = o >> 7, c16 = (o >> 4) & 7;                                              \
      int vsrc = row * 4096 + (KT) * 128 + (((c16 ^ (row & 7))) << 4);                   \
      __builtin_amdgcn_global_load_lds(                                                  \
          (const __attribute__((address_space(1))) void*)(Vb + vsrc),                    \
          (__attribute__((address_space(3))) void*)((char*)Vs[BUF] + o), 16, 0, 0);      \
    }                                                                                    \
  }

  STAGE(0, 0);
  __syncthreads();

  for (int kt = 0; kt < nt; ++kt) {
    const int buf = kt & 1;
    if (kt + 1 < nt) STAGE(kt + 1, buf ^ 1);

    if (kt < tripsB) {
      const bool diag = (kt == tripsB - 1);
      const int khmax = (diag && ((q0wB & 32) == 0)) ? 1 : 2;
      attn_tile(Ks[buf], Vs[buf], qfB, oaB, obB, mrunB, lsumB, kt, diag, khmax, qgB, q, hi);
    }
    if (kt < tripsA) {
      const bool diag = (kt == tripsA - 1);
      const int khmax = (diag && ((q0wA & 32) == 0)) ? 1 : 2;
      attn_tile(Ks[buf], Vs[buf], qfA, oaA, obA, mrunA, lsumA, kt, diag, khmax, qgA, q, hi);
    }
    __syncthreads();
  }

  const int b = bh >> 4, h = bh & 15;
#define EPI(OA, OB, LS, QG)                                                \
  {                                                                        \
    const float inv = 1.f / (LS);                                          \
    short* orow = Xb + (long)(b * 2048 + (QG)) * 1024 + h * 64;            \
    _Pragma("unroll") for (int g = 0; g < 4; ++g) {                        \
      unsigned u0 = cvtpk((OA)[4 * g] * inv, (OA)[4 * g + 1] * inv);       \
      unsigned u1 = cvtpk((OA)[4 * g + 2] * inv, (OA)[4 * g + 3] * inv);   \
      uint2 uu = {u0, u1};                                                 \
      *(uint2*)(orow + 8 * g + 4 * hi) = uu;                               \
      unsigned w0 = cvtpk((OB)[4 * g] * inv, (OB)[4 * g + 1] * inv);       \
      unsigned w1 = cvtpk((OB)[4 * g + 2] * inv, (OB)[4 * g + 3] * inv);   \
      uint2 ww = {w0, w1};                                                 \
      *(uint2*)(orow + 32 + 8 * g + 4 * hi) = ww;                          \
    }                                                                      \
  }
  EPI(oaA, obA, lsumA, qgA);
  EPI(oaB, obB, lsumB, qgB);
#undef EPI
}

// ---------------------------------------------------------------- launch
extern "C" void kernel_launch(void* const* d_in, const int* in_sizes, int n_in,
                              void* d_out, int out_size, void* d_ws, size_t ws_size,
                              hipStream_t stream) {
  const float* q  = (const float*)d_in[0];
  const float* k  = (const float*)d_in[1];
  const float* v  = (const float*)d_in[2];
  // d_in[3] = causal tril mask, hardcoded in attn_fwd
  const float* wq = (const float*)d_in[4];
  const float* wk = (const float*)d_in[5];
  const float* wv = (const float*)d_in[6];
  const float* wo = (const float*)d_in[7];

  short* ws = (short*)d_ws;
  const long T = 8388608;  // B*S*D
  short* Qh  = ws;
  short* Kh  = Qh + T;
  short* Vt  = Kh + T;
  short* Xb  = Vt + T;
  short* wqb = Xb + T;
  short* wkb = wqb + 1048576;
  short* wvb = wkb + 1048576;
  short* wob = wvb + 1048576;

  cvt4_bf16<<<dim3(512, 4), 256, 0, stream>>>(wq, wk, wv, wo, wqb, 1048576);

  // Q pre-scaled by 0.125 * log2(e) for exp2-domain softmax.
  gemm_proj<0><<<512, 256, 0, stream>>>(q, wqb, Qh, 0.18033688f);
  gemm_proj<0><<<512, 256, 0, stream>>>(k, wkb, Kh, 1.0f);
  gemm_proj<1><<<512, 256, 0, stream>>>(v, wvb, Vt, 1.0f);
  attn_fwd<<<dim3(64, 8), 256, 0, stream>>>(Qh, Kh, Vt, Xb);
  gemm_out<<<512, 256, 0, stream>>>(Xb, wob, (float*)d_out);
}

// Round 15
// 196.467 us; speedup vs baseline: 1.5046x; 1.0128x over previous
//
#include <hip/hip_runtime.h>
#include <hip/hip_bf16.h>

typedef __attribute__((ext_vector_type(8))) short bf16x8;
typedef __attribute__((ext_vector_type(4))) float f32x4;
typedef __attribute__((ext_vector_type(16))) float f32x16;

#define MFMA16(a, b, c) __builtin_amdgcn_mfma_f32_16x16x32_bf16((a), (b), (c), 0, 0, 0)
#define MFMA32(a, b, c) __builtin_amdgcn_mfma_f32_32x32x16_bf16((a), (b), (c), 0, 0, 0)

#if defined(__has_builtin)
#if __has_builtin(__builtin_amdgcn_exp2f)
#define EXP2(x) __builtin_amdgcn_exp2f(x)
#endif
#endif
#ifndef EXP2
#define EXP2(x) exp2f(x)
#endif

__device__ __forceinline__ short f2b(float f) {
  unsigned u = __builtin_bit_cast(unsigned, f);
  u += 0x7FFFu + ((u >> 16) & 1u);
  return (short)(u >> 16);
}
__device__ __forceinline__ unsigned cvtpk(float lo, float hi) {
  unsigned r;
  asm("v_cvt_pk_bf16_f32 %0, %1, %2" : "=v"(r) : "v"(lo), "v"(hi));
  return r;
}
__device__ __forceinline__ bf16x8 cvt8(float4 a, float4 b) {
  bf16x8 o;
  o[0] = f2b(a.x); o[1] = f2b(a.y); o[2] = f2b(a.z); o[3] = f2b(a.w);
  o[4] = f2b(b.x); o[5] = f2b(b.y); o[6] = f2b(b.z); o[7] = f2b(b.w);
  return o;
}

// ---------------------------------------------------------------- converts (weights only)
__global__ __launch_bounds__(256) void cvt4_bf16(const float* __restrict__ s0,
                                                 const float* __restrict__ s1,
                                                 const float* __restrict__ s2,
                                                 const float* __restrict__ s3,
                                                 short* __restrict__ d, long stride) {
  const int which = blockIdx.y;
  const float* s = which == 0 ? s0 : (which == 1 ? s1 : (which == 2 ? s2 : s3));
  long i = (long)blockIdx.x * 256 + threadIdx.x;
  const float4* sp = (const float4*)s;
  *(bf16x8*)(d + which * stride + i * 8) = cvt8(sp[2 * i], sp[2 * i + 1]);
}

// ---------------------------------------------------------------- projection GEMM
// Single-buffer LDS + T14 async split (R14 proven). A f32 -> bf16 in staging.
template <int MODE>
__global__ __launch_bounds__(256) void gemm_proj(const float* __restrict__ A_,
                                                 const short* __restrict__ BT_,
                                                 short* __restrict__ Cout,
                                                 float oscale) {
  __shared__ __align__(16) short As[128 * 64];
  __shared__ __align__(16) short Bs[128 * 64];
  const int t = threadIdx.x;
  const int l = t & 63, w = t >> 6;
  const int grp = l >> 4, li = l & 15;
  const int wg = (((int)blockIdx.x & 7) << 6) | ((int)blockIdx.x >> 3);  // T1 swizzle
  const int bm = wg >> 3, bn = wg & 7;
  const int m0 = bm << 7, n0 = bn << 7;
  const int wm = (w >> 1) << 6, wn = (w & 1) << 6;
  const int srow = t >> 3, scol = (t & 7) << 3;
  f32x4 acc[4][4] = {};

  float4 pa[4][2];
  bf16x8 pb[4];
#define PLOAD(KT)                                                            \
  {                                                                          \
    _Pragma("unroll") for (int i = 0; i < 4; ++i) {                          \
      const float* ga = A_ + (long)(m0 + i * 32 + srow) * 1024 + (KT) * 64 + scol; \
      pa[i][0] = *(const float4*)ga;                                         \
      pa[i][1] = *(const float4*)(ga + 4);                                   \
      pb[i] = *(const bf16x8*)(BT_ + (long)(n0 + i * 32 + srow) * 1024 + (KT) * 64 + scol); \
    }                                                                        \
  }
#define PWRITE()                                                             \
  {                                                                          \
    _Pragma("unroll") for (int i = 0; i < 4; ++i) {                          \
      *(bf16x8*)&As[i * 2048 + t * 8] = cvt8(pa[i][0], pa[i][1]);            \
      *(bf16x8*)&Bs[i * 2048 + t * 8] = pb[i];                               \
    }                                                                        \
  }

  PLOAD(0);
  PWRITE();
  __syncthreads();
#pragma unroll 1
  for (int kt = 0; kt < 16; ++kt) {
    if (kt + 1 < 16) PLOAD(kt + 1);  // in flight during compute (T14)
#pragma unroll
    for (int kk = 0; kk < 64; kk += 32) {
      bf16x8 af[4], bfr[4];
#pragma unroll
      for (int mi = 0; mi < 4; ++mi)
        af[mi] = *(const bf16x8*)&As[(wm + mi * 16 + li) * 64 + kk + grp * 8];
#pragma unroll
      for (int ni = 0; ni < 4; ++ni)
        bfr[ni] = *(const bf16x8*)&Bs[(wn + ni * 16 + li) * 64 + kk + grp * 8];
#pragma unroll
      for (int mi = 0; mi < 4; ++mi)
#pragma unroll
        for (int ni = 0; ni < 4; ++ni)
          acc[mi][ni] = MFMA16(af[mi], bfr[ni], acc[mi][ni]);
    }
    __syncthreads();  // all waves done reading As/Bs
    if (kt + 1 < 16) {
      PWRITE();
      __syncthreads();  // ds_writes visible
    }
  }
#undef PLOAD
#undef PWRITE
#pragma unroll
  for (int mi = 0; mi < 4; ++mi) {
#pragma unroll
    for (int ni = 0; ni < 4; ++ni) {
      f32x4 v = acc[mi][ni];
      int n = n0 + wn + ni * 16 + li;
#pragma unroll
      for (int r = 0; r < 4; ++r) {
        int m = m0 + wm + mi * 16 + grp * 4 + r;
        int b = m >> 11, sq = m & 2047;
        int h = n >> 6, dh = n & 63;
        if (MODE == 0)
          Cout[(((long)(b * 16 + h) * 2048 + sq) << 6) + dh] = f2b(v[r] * oscale);
        else
          Cout[(((long)(b * 16 + h) * 64 + dh) << 11) + sq] = f2b(v[r]);
      }
    }
  }
}

// ---------------------------------------------------------------- output GEMM (R14 proven)
__global__ __launch_bounds__(256) void gemm_out(const short* __restrict__ A_,
                                                const short* __restrict__ BT_,
                                                float* __restrict__ Cout) {
  __shared__ __align__(16) short As[128 * 64];
  __shared__ __align__(16) short Bs[128 * 64];
  const int t = threadIdx.x;
  const int l = t & 63, w = t >> 6;
  const int grp = l >> 4, li = l & 15;
  const int wg = (((int)blockIdx.x & 7) << 6) | ((int)blockIdx.x >> 3);  // T1 swizzle
  const int bm = wg >> 3, bn = wg & 7;
  const int m0 = bm << 7, n0 = bn << 7;
  const int wm = (w >> 1) << 6, wn = (w & 1) << 6;
  const int srow = t >> 3, scol = (t & 7) << 3;
  f32x4 acc[4][4] = {};
#pragma unroll 1
  for (int kt = 0; kt < 16; ++kt) {
#pragma unroll
    for (int i = 0; i < 4; ++i) {
      const short* ga = A_ + (long)(m0 + i * 32 + srow) * 1024 + kt * 64 + scol;
      __builtin_amdgcn_global_load_lds(
          (const __attribute__((address_space(1))) void*)ga,
          (__attribute__((address_space(3))) void*)&As[i * 2048 + t * 8], 16, 0, 0);
      const short* gb = BT_ + (long)(n0 + i * 32 + srow) * 1024 + kt * 64 + scol;
      __builtin_amdgcn_global_load_lds(
          (const __attribute__((address_space(1))) void*)gb,
          (__attribute__((address_space(3))) void*)&Bs[i * 2048 + t * 8], 16, 0, 0);
    }
    __syncthreads();
#pragma unroll
    for (int kk = 0; kk < 64; kk += 32) {
      bf16x8 af[4], bfr[4];
#pragma unroll
      for (int mi = 0; mi < 4; ++mi)
        af[mi] = *(const bf16x8*)&As[(wm + mi * 16 + li) * 64 + kk + grp * 8];
#pragma unroll
      for (int ni = 0; ni < 4; ++ni)
        bfr[ni] = *(const bf16x8*)&Bs[(wn + ni * 16 + li) * 64 + kk + grp * 8];
#pragma unroll
      for (int mi = 0; mi < 4; ++mi)
#pragma unroll
        for (int ni = 0; ni < 4; ++ni)
          acc[mi][ni] = MFMA16(af[mi], bfr[ni], acc[mi][ni]);
    }
    __syncthreads();
  }
#pragma unroll
  for (int mi = 0; mi < 4; ++mi) {
#pragma unroll
    for (int ni = 0; ni < 4; ++ni) {
      f32x4 v = acc[mi][ni];
      int n = n0 + wn + ni * 16 + li;
#pragma unroll
      for (int r = 0; r < 4; ++r) {
        int m = m0 + wm + mi * 16 + grp * 4 + r;
        Cout[(long)m * 1024 + n] = v[r];
      }
    }
  }
}

// ---------------------------------------------------------------- attention v9
// attn_tile math byte-identical (R6/R11 proven). Skeleton change only:
// 2 K-tiles staged per barrier phase (pair-buffers, 64KB LDS — free at 2
// blocks/CU). Up to 4 independent attn_tile calls per phase -> tile 2p+1's
// QK MFMAs overlap tile 2p's softmax VALU (T15 mechanism); barriers halved.
__device__ __forceinline__ void attn_tile(const short* Kbuf, const short* Vbuf,
                                          const bf16x8 qf[4], f32x16& oa, f32x16& ob,
                                          float& mrun, float& lsum, int kt, bool diag,
                                          int khmax, int qg, int q, int hi) {
  f32x16 p0 = {}, p1 = {};
  __builtin_amdgcn_s_setprio(1);
#pragma unroll
  for (int kd = 0; kd < 4; ++kd) {
    int colB = kd * 32 + hi * 16;
    bf16x8 kf0 = *(const bf16x8*)((const char*)Kbuf + q * 128 + (colB ^ ((q & 7) << 4)));
    p0 = MFMA32(kf0, qf[kd], p0);
  }
  if (khmax == 2) {
#pragma unroll
    for (int kd = 0; kd < 4; ++kd) {
      int colB = kd * 32 + hi * 16;
      bf16x8 kf1 = *(const bf16x8*)((const char*)Kbuf + (q + 32) * 128 + (colB ^ ((q & 7) << 4)));
      p1 = MFMA32(kf1, qf[kd], p1);
    }
  }
  __builtin_amdgcn_s_setprio(0);
  if (diag) {
#pragma unroll
    for (int r = 0; r < 16; ++r) {
      int key0 = kt * 64 + (r & 3) + 8 * (r >> 2) + 4 * hi;
      if (key0 > qg) p0[r] = -1e30f;
      if (key0 + 32 > qg) p1[r] = -1e30f;
    }
  }
  float pm = p0[0];
#pragma unroll
  for (int r = 1; r < 16; ++r) pm = fmaxf(pm, p0[r]);
  if (khmax == 2) {
#pragma unroll
    for (int r = 0; r < 16; ++r) pm = fmaxf(pm, p1[r]);
  }
  pm = fmaxf(pm, __shfl_xor(pm, 32));
  const bool skip = __all(pm - mrun <= 11.5f);  // T13 defer-max (log2 units)
  float mn;
  float alpha = 1.f;
  if (skip) {
    mn = mrun;
  } else {
    mn = fmaxf(mrun, pm);
    alpha = EXP2(mrun - mn);
    mrun = mn;
  }
  float ts = 0.f;
#pragma unroll
  for (int r = 0; r < 16; ++r) { p0[r] = EXP2(p0[r] - mn); ts += p0[r]; }
  if (khmax == 2) {
#pragma unroll
    for (int r = 0; r < 16; ++r) { p1[r] = EXP2(p1[r] - mn); ts += p1[r]; }
  }
  ts += __shfl_xor(ts, 32);
  if (skip) {
    lsum += ts;
  } else {
    lsum = lsum * alpha + ts;
#pragma unroll
    for (int r = 0; r < 16; ++r) { oa[r] *= alpha; ob[r] *= alpha; }
  }
  unsigned own0[8], prt0[8], own1[8], prt1[8];
#pragma unroll
  for (int g = 0; g < 4; ++g) {
    own0[2 * g]     = cvtpk(p0[4 * g], p0[4 * g + 1]);
    own0[2 * g + 1] = cvtpk(p0[4 * g + 2], p0[4 * g + 3]);
  }
#pragma unroll
  for (int i = 0; i < 8; ++i) prt0[i] = __shfl_xor(own0[i], 32);
  if (khmax == 2) {
#pragma unroll
    for (int g = 0; g < 4; ++g) {
      own1[2 * g]     = cvtpk(p1[4 * g], p1[4 * g + 1]);
      own1[2 * g + 1] = cvtpk(p1[4 * g + 2], p1[4 * g + 3]);
    }
#pragma unroll
    for (int i = 0; i < 8; ++i) prt1[i] = __shfl_xor(own1[i], 32);
  }
  __builtin_amdgcn_s_setprio(1);
#define PVSTEP(KD, OWN, PRT)                                                              \
  {                                                                                       \
    const int kdl = (KD) & 1;                                                             \
    unsigned b0 = hi ? PRT[4 * kdl + 2] : OWN[4 * kdl];                                   \
    unsigned b1 = hi ? PRT[4 * kdl + 3] : OWN[4 * kdl + 1];                               \
    unsigned b2 = hi ? OWN[4 * kdl + 2] : PRT[4 * kdl];                                   \
    unsigned b3 = hi ? OWN[4 * kdl + 3] : PRT[4 * kdl + 1];                               \
    int4 bi = {(int)b0, (int)b1, (int)b2, (int)b3};                                       \
    bf16x8 pb = __builtin_bit_cast(bf16x8, bi);                                           \
    int colB = (KD) * 32 + hi * 16;                                                       \
    bf16x8 vf0 = *(const bf16x8*)((const char*)Vbuf + q * 128 + (colB ^ ((q & 7) << 4))); \
    bf16x8 vf1 = *(const bf16x8*)((const char*)Vbuf + (q + 32) * 128 + (colB ^ ((q & 7) << 4))); \
    oa = MFMA32(vf0, pb, oa);                                                             \
    ob = MFMA32(vf1, pb, ob);                                                             \
  }
  PVSTEP(0, own0, prt0);
  PVSTEP(1, own0, prt0);
  if (khmax == 2) {
    PVSTEP(2, own1, prt1);
    PVSTEP(3, own1, prt1);
  }
#undef PVSTEP
  __builtin_amdgcn_s_setprio(0);
}

__global__ __launch_bounds__(256, 2) void attn_fwd(const short* __restrict__ Qh,
                                                   const short* __restrict__ Kh,
                                                   const short* __restrict__ Vt,
                                                   short* __restrict__ Xb) {
  // pair-buffers: [2 pair-slots][2 tiles x 4096 shorts]
  __shared__ __align__(16) short Ks[2][8192];
  __shared__ __align__(16) short Vs[2][8192];
  const int bh = blockIdx.x;
  const int qtA = blockIdx.y;        // 0..7 (light)
  const int qtB = 15 - qtA;          // heavy partner
  const int t = threadIdx.x, l = t & 63, w = t >> 6;
  const int q = l & 31, hi = l >> 5;
  const int q0wA = qtA * 128 + w * 32, q0wB = qtB * 128 + w * 32;
  const int qgA = q0wA + q, qgB = q0wB + q;
  const short* Qp = Qh + (long)bh * 131072;
  const char* Kb = (const char*)(Kh + (long)bh * 131072);
  const char* Vb = (const char*)(Vt + (long)bh * 131072);

  bf16x8 qfA[4], qfB[4];
#pragma unroll
  for (int kd = 0; kd < 4; ++kd) {
    qfA[kd] = *(const bf16x8*)(Qp + (long)qgA * 64 + kd * 16 + hi * 8);
    qfB[kd] = *(const bf16x8*)(Qp + (long)qgB * 64 + kd * 16 + hi * 8);
  }

  const int co0 = t * 16, co1 = co0 + 4096;

  f32x16 oaA = {}, obA = {}, oaB = {}, obB = {};
  float mrunA = -1e30f, lsumA = 0.f, mrunB = -1e30f, lsumB = 0.f;
  const int tripsA = (q0wA >> 6) + 1;
  const int tripsB = (q0wB >> 6) + 1;
  const int npairs = qtB + 1;  // nt = 2*npairs tiles, always even

  // stage 2 tiles (2*(K8KB+V8KB)=32KB) of pair P into slot BUF
#define STAGEP(P, BUF)                                                                   \
  {                                                                                      \
    _Pragma("unroll") for (int tl = 0; tl < 2; ++tl) {                                   \
      long ktb = (long)(2 * (P) + tl) * 8192;                                            \
      _Pragma("unroll") for (int c = 0; c < 2; ++c) {                                    \
        int o = c ? co1 : co0;                                                           \
        int ksrc = o ^ (((o >> 7) & 7) << 4);                                            \
        __builtin_amdgcn_global_load_lds(                                                \
            (const __attribute__((address_space(1))) void*)(Kb + ktb + ksrc),            \
            (__attribute__((address_space(3))) void*)((char*)Ks[BUF] + tl * 8192 + o),   \
            16, 0, 0);                                                                   \
        int row = o >> 7, c16 = (o >> 4) & 7;                                            \
        int vsrc = row * 4096 + (2 * (P) + tl) * 128 + (((c16 ^ (row & 7))) << 4);       \
        __builtin_amdgcn_global_load_lds(                                                \
            (const __attribute__((address_space(1))) void*)(Vb + vsrc),                  \
            (__attribute__((address_space(3))) void*)((char*)Vs[BUF] + tl * 8192 + o),   \
            16, 0, 0);                                                                   \
      }                                                                                  \
    }                                                                                    \
  }

  STAGEP(0, 0);
  __syncthreads();

  for (int p = 0; p < npairs; ++p) {
    const int buf = p & 1;
    if (p + 1 < npairs) STAGEP(p + 1, buf ^ 1);

#pragma unroll
    for (int sub = 0; sub < 2; ++sub) {
      const int kt = 2 * p + sub;
      const short* Kt = Ks[buf] + sub * 4096;
      const short* Vtl = Vs[buf] + sub * 4096;
      if (kt < tripsB) {
        const bool diag = (kt == tripsB - 1);
        const int khmax = (diag && ((q0wB & 32) == 0)) ? 1 : 2;
        attn_tile(Kt, Vtl, qfB, oaB, obB, mrunB, lsumB, kt, diag, khmax, qgB, q, hi);
      }
      if (kt < tripsA) {
        const bool diag = (kt == tripsA - 1);
        const int khmax = (diag && ((q0wA & 32) == 0)) ? 1 : 2;
        attn_tile(Kt, Vtl, qfA, oaA, obA, mrunA, lsumA, kt, diag, khmax, qgA, q, hi);
      }
    }
    __syncthreads();
  }

  const int b = bh >> 4, h = bh & 15;
#define EPI(OA, OB, LS, QG)                                                \
  {                                                                        \
    const float inv = 1.f / (LS);                                          \
    short* orow = Xb + (long)(b * 2048 + (QG)) * 1024 + h * 64;            \
    _Pragma("unroll") for (int g = 0; g < 4; ++g) {                        \
      unsigned u0 = cvtpk((OA)[4 * g] * inv, (OA)[4 * g + 1] * inv);       \
      unsigned u1 = cvtpk((OA)[4 * g + 2] * inv, (OA)[4 * g + 3] * inv);   \
      uint2 uu = {u0, u1};                                                 \
      *(uint2*)(orow + 8 * g + 4 * hi) = uu;                               \
      unsigned w0 = cvtpk((OB)[4 * g] * inv, (OB)[4 * g + 1] * inv);       \
      unsigned w1 = cvtpk((OB)[4 * g + 2] * inv, (OB)[4 * g + 3] * inv);   \
      uint2 ww = {w0, w1};                                                 \
      *(uint2*)(orow + 32 + 8 * g + 4 * hi) = ww;                          \
    }                                                                      \
  }
  EPI(oaA, obA, lsumA, qgA);
  EPI(oaB, obB, lsumB, qgB);
#undef EPI
}

// ---------------------------------------------------------------- launch
extern "C" void kernel_launch(void* const* d_in, const int* in_sizes, int n_in,
                              void* d_out, int out_size, void* d_ws, size_t ws_size,
                              hipStream_t stream) {
  const float* q  = (const float*)d_in[0];
  const float* k  = (const float*)d_in[1];
  const float* v  = (const float*)d_in[2];
  // d_in[3] = causal tril mask, hardcoded in attn_fwd
  const float* wq = (const float*)d_in[4];
  const float* wk = (const float*)d_in[5];
  const float* wv = (const float*)d_in[6];
  const float* wo = (const float*)d_in[7];

  short* ws = (short*)d_ws;
  const long T = 8388608;  // B*S*D
  short* Qh  = ws;
  short* Kh  = Qh + T;
  short* Vt  = Kh + T;
  short* Xb  = Vt + T;
  short* wqb = Xb + T;
  short* wkb = wqb + 1048576;
  short* wvb = wkb + 1048576;
  short* wob = wvb + 1048576;

  cvt4_bf16<<<dim3(512, 4), 256, 0, stream>>>(wq, wk, wv, wo, wqb, 1048576);

  // Q pre-scaled by 0.125 * log2(e) for exp2-domain softmax.
  gemm_proj<0><<<512, 256, 0, stream>>>(q, wqb, Qh, 0.18033688f);
  gemm_proj<0><<<512, 256, 0, stream>>>(k, wkb, Kh, 1.0f);
  gemm_proj<1><<<512, 256, 0, stream>>>(v, wvb, Vt, 1.0f);
  attn_fwd<<<dim3(64, 8), 256, 0, stream>>>(Qh, Kh, Vt, Xb);
  gemm_out<<<512, 256, 0, stream>>>(Xb, wob, (float*)d_out);
}